// Round 16
// baseline (65.836 us; speedup 1.0000x reference)
//
#include <hip/hip_runtime.h>
#include <hip/hip_bf16.h>
#include <math.h>

#define S_LEN 1024
#define BATCH 32
#define EMB   128
#define NHEAD 4
#define HDIM  32
#define BHN   (BATCH*NHEAD)          // 128
#define HBUF  (BHN*S_LEN*HDIM)       // 4194304 elements per q/k/v (bf16)
#define NTOK  (S_LEN*BATCH)          // 32768

typedef __attribute__((ext_vector_type(4))) float f32x4;
typedef __attribute__((ext_vector_type(8))) short bf16x8;
typedef __attribute__((ext_vector_type(4))) short bf16x4;
typedef __attribute__((ext_vector_type(2))) unsigned int u32x2;
typedef __attribute__((ext_vector_type(4))) unsigned int u32x4;

// (1/sqrt(32)) * log2(e): folded into Wq/bq by wcvt_kernel
#define Q_PRESCALE 0.25503588f

__device__ __forceinline__ unsigned short f2bf(float f) {
    union { float f; unsigned u; } v; v.f = f;
    unsigned r = v.u + 0x7fff + ((v.u >> 16) & 1);   // RNE
    return (unsigned short)(r >> 16);
}

__device__ __forceinline__ void gl_lds16(const void* g, void* l) {
    __builtin_amdgcn_global_load_lds(
        (const __attribute__((address_space(1))) unsigned*)g,
        (__attribute__((address_space(3))) unsigned*)l, 16, 0, 0);
}

// ---------------- Kernel 0: weight/bias convert (fp32 -> bf16) -------------
__global__ __launch_bounds__(256)
void wcvt_kernel(const float* __restrict__ w, const float* __restrict__ bias,
                 const float* __restrict__ wo, const float* __restrict__ bo,
                 __hip_bfloat16* __restrict__ wbf,
                 __hip_bfloat16* __restrict__ wobf,
                 float* __restrict__ biasf)
{
    const int bid = blockIdx.x, tid = threadIdx.x;
    if (bid < 48) {
        int e = bid * 1024 + tid * 4;
        float4 v = *(const float4*)(w + e);
        float s = (e < 128 * 128) ? Q_PRESCALE : 1.f;
        bf16x4 o;
        o[0] = (short)f2bf(v.x * s); o[1] = (short)f2bf(v.y * s);
        o[2] = (short)f2bf(v.z * s); o[3] = (short)f2bf(v.w * s);
        *(bf16x4*)(wbf + e) = o;
    } else if (bid < 64) {
        int e = (bid - 48) * 1024 + tid * 4;
        float4 v = *(const float4*)(wo + e);
        bf16x4 o;
        o[0] = (short)f2bf(v.x); o[1] = (short)f2bf(v.y);
        o[2] = (short)f2bf(v.z); o[3] = (short)f2bf(v.w);
        *(bf16x4*)(wobf + e) = o;
    } else if (tid < 96) {
        int e = tid * 4;
        float4 v = *(const float4*)(bias + e);
        float s = (e < 128) ? Q_PRESCALE : 1.f;
        v.x *= s; v.y *= s; v.z *= s; v.w *= s;
        *(float4*)(biasf + e) = v;
    } else if (tid < 128) {
        int e = (tid - 96) * 4;
        *(float4*)(biasf + 384 + e) = *(const float4*)(bo + e);
    }
}

// ---------------- Kernel 1: QKV projection, bf16 MFMA ----------------
__global__ __launch_bounds__(256)
void qkv_mfma_kernel(const float* __restrict__ x,
                     const __hip_bfloat16* __restrict__ wbf,
                     const float* __restrict__ biasf,
                     __hip_bfloat16* __restrict__ qb,
                     __hip_bfloat16* __restrict__ kb,
                     __hip_bfloat16* __restrict__ vtb)
{
    __shared__ __align__(16) unsigned char smem[17408 + 32768];
    __hip_bfloat16* xs = (__hip_bfloat16*)smem;            // [64][136] padded
    __hip_bfloat16* wl = (__hip_bfloat16*)(smem + 17408);  // [128][128] XOR-swz
    const int tid   = threadIdx.x;
    const int mt    = blockIdx.x;
    const int which = blockIdx.y;        // 0=q 1=k 2=v
    const int b0 = (mt & 7) * 4;
    const int s0 = (mt >> 3) * 16;

    const __hip_bfloat16* wsec = wbf + which * (128 * 128);
    #pragma unroll
    for (int j = 0; j < 8; ++j) {
        int idx = tid + j * 256;
        int fl = idx >> 4, c = idx & 15;
        int cs = c ^ (fl & 15);
        gl_lds16(wsec + fl * 128 + cs * 8, wl + idx * 8);
    }
    #pragma unroll
    for (int j = 0; j < 8; ++j) {
        int idx = tid + j * 256;
        int lt = idx >> 5, c4 = idx & 31;
        int t = (s0 + (lt & 15)) * 32 + b0 + (lt >> 4);
        float4 v = *(const float4*)(x + (size_t)t * 128 + c4 * 4);
        bf16x4 o;
        o[0] = (short)f2bf(v.x); o[1] = (short)f2bf(v.y);
        o[2] = (short)f2bf(v.z); o[3] = (short)f2bf(v.w);
        *(bf16x4*)(xs + lt * 136 + c4 * 4) = o;
    }
    __syncthreads();

    const int wv = tid >> 6, wm = wv >> 1, wn = wv & 1;
    const int l = tid & 63, q15 = l & 15, g = l >> 4;

    bf16x8 xf[2][4];
    #pragma unroll
    for (int tt = 0; tt < 2; ++tt)
        #pragma unroll
        for (int kc = 0; kc < 4; ++kc)
            xf[tt][kc] = *(const bf16x8*)(xs + (wm * 32 + tt * 16 + q15) * 136
                                          + kc * 32 + 8 * g);

    f32x4 acc[4][2];
    #pragma unroll
    for (int nt = 0; nt < 4; ++nt)
        #pragma unroll
        for (int tt = 0; tt < 2; ++tt)
            acc[nt][tt] = (f32x4){0.f, 0.f, 0.f, 0.f};

    #pragma unroll
    for (int nt = 0; nt < 4; ++nt) {
        const int fl = wn * 64 + nt * 16 + q15;
        #pragma unroll
        for (int kc = 0; kc < 4; ++kc) {
            bf16x8 wf = *(const bf16x8*)(wl + fl * 128
                                         + (((kc * 4 + g) ^ q15) * 8));
            acc[nt][0] = __builtin_amdgcn_mfma_f32_16x16x32_bf16(wf, xf[0][kc], acc[nt][0], 0, 0, 0);
            acc[nt][1] = __builtin_amdgcn_mfma_f32_16x16x32_bf16(wf, xf[1][kc], acc[nt][1], 0, 0, 0);
        }
    }
    __syncthreads();
    __hip_bfloat16* ol = wl;

    if (which < 2) {
        #pragma unroll
        for (int nt = 0; nt < 4; ++nt) {
            float4 bv = *(const float4*)(biasf + which * 128 + wn * 64 + nt * 16 + 4 * g);
            #pragma unroll
            for (int tt = 0; tt < 2; ++tt) {
                bf16x4 pk;
                pk[0] = (short)f2bf(acc[nt][tt][0] + bv.x);
                pk[1] = (short)f2bf(acc[nt][tt][1] + bv.y);
                pk[2] = (short)f2bf(acc[nt][tt][2] + bv.z);
                pk[3] = (short)f2bf(acc[nt][tt][3] + bv.w);
                *(bf16x4*)(ol + (wm * 32 + tt * 16 + q15) * 136
                           + wn * 64 + nt * 16 + 4 * g) = pk;
            }
        }
        __syncthreads();
        const int bb = tid >> 6, rr = tid & 63, ss = rr >> 2, c4 = rr & 3;
        __hip_bfloat16* dst = (which == 0) ? qb : kb;
        #pragma unroll
        for (int i = 0; i < 4; ++i) {
            bf16x8 vv = *(const bf16x8*)(ol + (bb * 16 + ss) * 136 + i * 32 + c4 * 8);
            *(bf16x8*)(dst + ((size_t)((b0 + bb) * 4 + i)) * 32768
                       + (s0 + ss) * 32 + c4 * 8) = vv;
        }
    } else {
        #pragma unroll
        for (int nt = 0; nt < 4; ++nt) {
            float4 bv = *(const float4*)(biasf + 256 + wn * 64 + nt * 16 + 4 * g);
            const float* bvp = (const float*)&bv;
            #pragma unroll
            for (int tt = 0; tt < 2; ++tt) {
                #pragma unroll
                for (int r = 0; r < 4; ++r) {
                    int f = wn * 64 + nt * 16 + 4 * g + r;
                    ol[f * 72 + wm * 32 + tt * 16 + q15] =
                        __float2bfloat16(acc[nt][tt][r] + bvp[r]);
                }
            }
        }
        __syncthreads();
        const int bb = tid >> 6, rr = tid & 63, fln = rr >> 1, sh = rr & 1;
        #pragma unroll
        for (int i = 0; i < 4; ++i) {
            int f = i * 32 + fln;
            bf16x8 vv = *(const bf16x8*)(ol + f * 72 + bb * 16 + sh * 8);
            *(bf16x8*)(vtb + ((size_t)((b0 + bb) * 4 + i)) * 32768
                       + (size_t)fln * 1024 + s0 + sh * 8) = vv;
        }
    }
}

// ---------------- Kernel 2: flash attention, LDS-staged, register-P ---------
// grid (BH=128, 16), block 256 (4 waves x 16 queries). K/V double-buffered in
// LDS via global_load_lds; V tile 16B-granule XOR-swizzled. No softmax max
// (P = exp2(sc) unnormalized); P packed to bf16 IN REGISTERS and fed to PV
// as the A-operand with the sigma_g key permutation (keys sub*16+4g+r are
// exactly where swapped-QK^T leaves them); V read as B-operand b64 pairs in
// the SAME permuted order. Ones-B-operand MFMA gives lane-local row sums.
__global__ __launch_bounds__(256)
void attn_kernel(const __hip_bfloat16* __restrict__ qg,
                 const __hip_bfloat16* __restrict__ kg,
                 const __hip_bfloat16* __restrict__ vtg,
                 __hip_bfloat16* __restrict__ att)
{
    __shared__ __hip_bfloat16 Kl[2][64 * 32];
    __shared__ __hip_bfloat16 Vl[2][32 * 64];

    const int tid = threadIdx.x;
    const int w   = tid >> 6;
    const int l   = tid & 63;
    const int q15 = l & 15;
    const int g   = l >> 4;
    const int bh  = blockIdx.x;
    const int qt  = blockIdx.y;

    const __hip_bfloat16* kp  = kg  + (size_t)bh * (S_LEN * HDIM);
    const __hip_bfloat16* vtp = vtg + (size_t)bh * (HDIM * S_LEN);

    bf16x8 qf = *(const bf16x8*)(qg + (size_t)bh * (S_LEN * HDIM)
                                 + (size_t)(qt * 64 + w * 16 + q15) * HDIM + 8 * g);

    f32x4 acc0 = {0.f, 0.f, 0.f, 0.f};
    f32x4 acc1 = {0.f, 0.f, 0.f, 0.f};
    f32x4 accs = {0.f, 0.f, 0.f, 0.f};

    const short ONE = (short)0x3F80;
    const bf16x8 onef = {ONE, ONE, ONE, ONE, ONE, ONE, ONE, ONE};

    const int kkey = tid >> 2, kd0 = (tid & 3) * 8;
    // V staging: LDS 16B-granule c of row vd holds global granule c^(vd&7)
    const int vd = tid >> 3, vg0 = ((tid & 7) ^ (vd & 7)) * 8;

    gl_lds16(kp + (size_t)kkey * HDIM + kd0, (void*)(&Kl[0][0] + tid * 8));
    gl_lds16(vtp + (size_t)vd * S_LEN + vg0, (void*)(&Vl[0][0] + tid * 8));
    __syncthreads();

    // V read addressing (per lane): rows d0=q15, d1=16+q15 (same &7), byte
    // offset within 16B granule = (g&1)*8; global granule Ga=kc*4+(g>>1),
    // Gb=Ga+2; LDS granule = G ^ (row&7).
    const int vxor = q15 & 7;
    const int vbo  = (g & 1) * 8;
    const int gh   = g >> 1;

    int cur = 0;
    for (int kt = 0; kt < 16; ++kt) {
        if (kt + 1 < 16) {
            const int kb2 = (kt + 1) * 64;
            gl_lds16(kp + (size_t)(kb2 + kkey) * HDIM + kd0,
                     (void*)(&Kl[cur ^ 1][0] + tid * 8));
            gl_lds16(vtp + (size_t)vd * S_LEN + kb2 + vg0,
                     (void*)(&Vl[cur ^ 1][0] + tid * 8));
        }

        // ---- QK^T: 4 MFMAs (lane(q15,g): sc[sub][r] = S[key=sub*16+4g+r][q15])
        f32x4 sc[4];
        #pragma unroll
        for (int sub = 0; sub < 4; ++sub) {
            bf16x8 kf = *(const bf16x8*)(&Kl[cur][(sub * 16 + q15) * HDIM + 8 * g]);
            f32x4 z = {0.f, 0.f, 0.f, 0.f};
            sc[sub] = __builtin_amdgcn_mfma_f32_16x16x32_bf16(kf, qf, z, 0, 0, 0);
        }

        // ---- V B-fragments from LDS (swizzled b64 pairs, permuted key order)
        const char* vbase = (const char*)&Vl[cur][0];
        bf16x8 vf[2][2];   // [kc][dtile]
        #pragma unroll
        for (int kc = 0; kc < 2; ++kc) {
            const int Ga = kc * 4 + gh, Gb = Ga + 2;
            bf16x4 a0 = *(const bf16x4*)(vbase + q15 * 128 + ((Ga ^ vxor) * 16) + vbo);
            bf16x4 a1 = *(const bf16x4*)(vbase + q15 * 128 + ((Gb ^ vxor) * 16) + vbo);
            bf16x4 b0 = *(const bf16x4*)(vbase + (16 + q15) * 128 + ((Ga ^ vxor) * 16) + vbo);
            bf16x4 b1 = *(const bf16x4*)(vbase + (16 + q15) * 128 + ((Gb ^ vxor) * 16) + vbo);
            vf[kc][0] = __builtin_shufflevector(a0, a1, 0, 1, 2, 3, 4, 5, 6, 7);
            vf[kc][1] = __builtin_shufflevector(b0, b1, 0, 1, 2, 3, 4, 5, 6, 7);
        }

        // ---- P = exp2(sc) packed to bf16 A-fragments IN REGISTERS
        // pf0 (kc0): keys {4g..4g+3, 16+4g..16+4g+3} = subs 0,1
        // pf1 (kc1): subs 2,3
        bf16x8 pf0, pf1;
        {
            u32x4 t;
            float e0, e1, e2, e3, e4, e5, e6, e7;
#define PACKP(dst, SA, SB)                                                \
            e0 = __builtin_amdgcn_exp2f(SA[0]);                           \
            e1 = __builtin_amdgcn_exp2f(SA[1]);                           \
            e2 = __builtin_amdgcn_exp2f(SA[2]);                           \
            e3 = __builtin_amdgcn_exp2f(SA[3]);                           \
            e4 = __builtin_amdgcn_exp2f(SB[0]);                           \
            e5 = __builtin_amdgcn_exp2f(SB[1]);                           \
            e6 = __builtin_amdgcn_exp2f(SB[2]);                           \
            e7 = __builtin_amdgcn_exp2f(SB[3]);                           \
            t[0] = __builtin_amdgcn_perm(__float_as_uint(e1),             \
                                         __float_as_uint(e0), 0x07060302u); \
            t[1] = __builtin_amdgcn_perm(__float_as_uint(e3),             \
                                         __float_as_uint(e2), 0x07060302u); \
            t[2] = __builtin_amdgcn_perm(__float_as_uint(e5),             \
                                         __float_as_uint(e4), 0x07060302u); \
            t[3] = __builtin_amdgcn_perm(__float_as_uint(e7),             \
                                         __float_as_uint(e6), 0x07060302u); \
            __builtin_memcpy(&dst, &t, 16);

            PACKP(pf0, sc[0], sc[1])
            PACKP(pf1, sc[2], sc[3])
#undef PACKP
        }

        // ---- PV + ones row-sum: 6 MFMAs, P from registers
        acc0 = __builtin_amdgcn_mfma_f32_16x16x32_bf16(pf0, vf[0][0], acc0, 0, 0, 0);
        acc1 = __builtin_amdgcn_mfma_f32_16x16x32_bf16(pf0, vf[0][1], acc1, 0, 0, 0);
        accs = __builtin_amdgcn_mfma_f32_16x16x32_bf16(pf0, onef, accs, 0, 0, 0);
        acc0 = __builtin_amdgcn_mfma_f32_16x16x32_bf16(pf1, vf[1][0], acc0, 0, 0, 0);
        acc1 = __builtin_amdgcn_mfma_f32_16x16x32_bf16(pf1, vf[1][1], acc1, 0, 0, 0);
        accs = __builtin_amdgcn_mfma_f32_16x16x32_bf16(pf1, onef, accs, 0, 0, 0);

        __syncthreads();   // drains vmcnt: next tile staged; compute done
        cur ^= 1;
    }

    // ---- epilogue: normalize by ones row sums (lane-local), write bf16
    // acc0[r] = O[q=4g+r][d=q15], acc1[r] = O[q=4g+r][d=16+q15]
    const int b = bh >> 2, h = bh & 3;
    #pragma unroll
    for (int r = 0; r < 4; ++r) {
        const float inv = 1.f / accs[r];
        const int srow = qt * 64 + w * 16 + 4 * g + r;
        __hip_bfloat16* ap = att + ((size_t)srow * BATCH + b) * EMB + h * HDIM;
        ap[q15]      = __float2bfloat16(acc0[r] * inv);
        ap[16 + q15] = __float2bfloat16(acc1[r] * inv);
    }
}

// ---------------- Kernel 3: out_proj MFMA + bias + residual + LayerNorm ----
__global__ __launch_bounds__(256)
void proj_ln_mfma(const float* __restrict__ x,
                  const __hip_bfloat16* __restrict__ att,
                  const __hip_bfloat16* __restrict__ wobf,
                  const float* __restrict__ biasf,
                  const float* __restrict__ gm, const float* __restrict__ bt,
                  float* __restrict__ out)
{
    __shared__ __align__(16) unsigned char smem[32768 + 16384 + 1024];
    __hip_bfloat16* wl = (__hip_bfloat16*)smem;              // [128][128] XOR-swz
    __hip_bfloat16* al = (__hip_bfloat16*)(smem + 32768);    // [64][128] XOR-swz
    float* red = (float*)(smem + 32768 + 16384);             // [2][128]

    const int tid = threadIdx.x;
    const int t0  = blockIdx.x * 64;

    #pragma unroll
    for (int j = 0; j < 8; ++j) {
        int idx = tid + j * 256;
        int fl = idx >> 4, c = idx & 15;
        int cs = c ^ (fl & 15);
        gl_lds16(wobf + fl * 128 + cs * 8, wl + idx * 8);
    }
    #pragma unroll
    for (int j = 0; j < 4; ++j) {
        int idx = tid + j * 256;
        int fl = idx >> 4, c = idx & 15;
        int cs = c ^ (fl & 15);
        gl_lds16(att + (size_t)(t0 + fl) * 128 + cs * 8, al + idx * 8);
    }
    __syncthreads();

    const int wv = tid >> 6, wm = wv >> 1, wn = wv & 1;
    const int l = tid & 63, q15 = l & 15, g = l >> 4;

    bf16x8 af[2][4];
    #pragma unroll
    for (int tt = 0; tt < 2; ++tt)
        #pragma unroll
        for (int kc = 0; kc < 4; ++kc)
            af[tt][kc] = *(const bf16x8*)(al + (wm * 32 + tt * 16 + q15) * 128
                                          + (((kc * 4 + g) ^ q15) * 8));

    f32x4 acc[4][2];
    #pragma unroll
    for (int nt = 0; nt < 4; ++nt)
        #pragma unroll
        for (int tt = 0; tt < 2; ++tt)
            acc[nt][tt] = (f32x4){0.f, 0.f, 0.f, 0.f};

    #pragma unroll
    for (int nt = 0; nt < 4; ++nt) {
        const int fl = wn * 64 + nt * 16 + q15;
        #pragma unroll
        for (int kc = 0; kc < 4; ++kc) {
            bf16x8 wf = *(const bf16x8*)(wl + fl * 128
                                         + (((kc * 4 + g) ^ q15) * 8));
            acc[nt][0] = __builtin_amdgcn_mfma_f32_16x16x32_bf16(wf, af[0][kc], acc[nt][0], 0, 0, 0);
            acc[nt][1] = __builtin_amdgcn_mfma_f32_16x16x32_bf16(wf, af[1][kc], acc[nt][1], 0, 0, 0);
        }
    }

    float vv[4][2][4];
    float psum[2] = {0.f, 0.f}, psq[2] = {0.f, 0.f};
    #pragma unroll
    for (int nt = 0; nt < 4; ++nt) {
        const int f0 = wn * 64 + nt * 16 + 4 * g;
        float4 bv = *(const float4*)(biasf + 384 + f0);
        const float* bvp = (const float*)&bv;
        #pragma unroll
        for (int tt = 0; tt < 2; ++tt) {
            const int t = t0 + wm * 32 + tt * 16 + q15;
            float4 xv = *(const float4*)(x + (size_t)t * 128 + f0);
            const float* xvp = (const float*)&xv;
            #pragma unroll
            for (int r = 0; r < 4; ++r) {
                float v = acc[nt][tt][r] + bvp[r] + xvp[r];
                vv[nt][tt][r] = v;
                psum[tt] += v;
                psq[tt]  = fmaf(v, v, psq[tt]);
            }
        }
    }
    #pragma unroll
    for (int tt = 0; tt < 2; ++tt) {
        psum[tt] += __shfl_xor(psum[tt], 16);
        psum[tt] += __shfl_xor(psum[tt], 32);
        psq[tt]  += __shfl_xor(psq[tt], 16);
        psq[tt]  += __shfl_xor(psq[tt], 32);
    }
    if (l < 16) {
        #pragma unroll
        for (int tt = 0; tt < 2; ++tt) {
            int idx = ((wn * 2 + wm) * 2 + tt) * 16 + q15;
            red[idx]       = psum[tt];
            red[128 + idx] = psq[tt];
        }
    }
    __syncthreads();

    float mean[2], rstd[2];
    #pragma unroll
    for (int tt = 0; tt < 2; ++tt) {
        int oidx = (((wn ^ 1) * 2 + wm) * 2 + tt) * 16 + q15;
        float s  = psum[tt] + red[oidx];
        float sq = psq[tt]  + red[128 + oidx];
        mean[tt] = s * (1.f / 128.f);
        float var = sq * (1.f / 128.f) - mean[tt] * mean[tt];
        rstd[tt] = rsqrtf(var + 1e-5f);
    }

    #pragma unroll
    for (int nt = 0; nt < 4; ++nt) {
        const int f0 = wn * 64 + nt * 16 + 4 * g;
        float4 gv  = *(const float4*)(gm + f0);
        float4 btv = *(const float4*)(bt + f0);
        const float* gvp = (const float*)&gv;
        const float* btp = (const float*)&btv;
        #pragma unroll
        for (int tt = 0; tt < 2; ++tt) {
            const int t = t0 + wm * 32 + tt * 16 + q15;
            float4 o;
            float* op = (float*)&o;
            #pragma unroll
            for (int r = 0; r < 4; ++r)
                op[r] = (vv[nt][tt][r] - mean[tt]) * rstd[tt] * gvp[r] + btp[r];
            *(float4*)(out + (size_t)t * 128 + f0) = o;
        }
    }
}

extern "C" void kernel_launch(void* const* d_in, const int* in_sizes, int n_in,
                              void* d_out, int out_size, void* d_ws, size_t ws_size,
                              hipStream_t stream) {
    const float* x     = (const float*)d_in[0];
    const float* wi    = (const float*)d_in[1];
    const float* bi    = (const float*)d_in[2];
    const float* wo    = (const float*)d_in[3];
    const float* bo    = (const float*)d_in[4];
    const float* gamma = (const float*)d_in[5];
    const float* beta  = (const float*)d_in[6];
    float* out = (float*)d_out;

    unsigned char* wsb = (unsigned char*)d_ws;
    __hip_bfloat16* wbf   = (__hip_bfloat16*)wsb;               // 98304 B
    __hip_bfloat16* wobf  = (__hip_bfloat16*)(wsb + 98304);     // 32768 B
    float*          biasf = (float*)(wsb + 131072);             // 2048 B
    __hip_bfloat16* qb    = (__hip_bfloat16*)(wsb + 133120);    // 8 MB each
    __hip_bfloat16* kb    = qb + HBUF;
    __hip_bfloat16* vtb   = kb + HBUF;
    __hip_bfloat16* att   = vtb + HBUF;                          // 8 MB

    wcvt_kernel<<<65, 256, 0, stream>>>(wi, bi, wo, bo, wbf, wobf, biasf);
    qkv_mfma_kernel<<<dim3(512, 3), 256, 0, stream>>>(x, wbf, biasf, qb, kb, vtb);
    attn_kernel<<<dim3(BHN, 16), 256, 0, stream>>>(qb, kb, vtb, att);
    proj_ln_mfma<<<512, 256, 0, stream>>>(x, att, wobf, biasf, gamma, beta, out);
}

// Round 19
// 65.645 us; speedup vs baseline: 1.0029x; 1.0029x over previous
//
#include <hip/hip_runtime.h>
#include <hip/hip_bf16.h>
#include <math.h>

#define S_LEN 1024
#define BATCH 32
#define EMB   128
#define NHEAD 4
#define HDIM  32
#define BHN   (BATCH*NHEAD)          // 128
#define HBUF  (BHN*S_LEN*HDIM)       // 4194304 elements per q/k/v (bf16)
#define NTOK  (S_LEN*BATCH)          // 32768

typedef __attribute__((ext_vector_type(4))) float f32x4;
typedef __attribute__((ext_vector_type(8))) short bf16x8;
typedef __attribute__((ext_vector_type(4))) short bf16x4;
typedef __attribute__((ext_vector_type(2))) unsigned int u32x2;
typedef __attribute__((ext_vector_type(4))) unsigned int u32x4;

// (1/sqrt(32)) * log2(e): folded into Wq/bq by wcvt_kernel
#define Q_PRESCALE 0.25503588f

__device__ __forceinline__ unsigned short f2bf(float f) {
    union { float f; unsigned u; } v; v.f = f;
    unsigned r = v.u + 0x7fff + ((v.u >> 16) & 1);   // RNE
    return (unsigned short)(r >> 16);
}

__device__ __forceinline__ void gl_lds16(const void* g, void* l) {
    __builtin_amdgcn_global_load_lds(
        (const __attribute__((address_space(1))) unsigned*)g,
        (__attribute__((address_space(3))) unsigned*)l, 16, 0, 0);
}

// ---------------- Kernel 0: weight/bias convert (fp32 -> bf16) -------------
__global__ __launch_bounds__(256)
void wcvt_kernel(const float* __restrict__ w, const float* __restrict__ bias,
                 const float* __restrict__ wo, const float* __restrict__ bo,
                 __hip_bfloat16* __restrict__ wbf,
                 __hip_bfloat16* __restrict__ wobf,
                 float* __restrict__ biasf)
{
    const int bid = blockIdx.x, tid = threadIdx.x;
    if (bid < 48) {
        int e = bid * 1024 + tid * 4;
        float4 v = *(const float4*)(w + e);
        float s = (e < 128 * 128) ? Q_PRESCALE : 1.f;
        bf16x4 o;
        o[0] = (short)f2bf(v.x * s); o[1] = (short)f2bf(v.y * s);
        o[2] = (short)f2bf(v.z * s); o[3] = (short)f2bf(v.w * s);
        *(bf16x4*)(wbf + e) = o;
    } else if (bid < 64) {
        int e = (bid - 48) * 1024 + tid * 4;
        float4 v = *(const float4*)(wo + e);
        bf16x4 o;
        o[0] = (short)f2bf(v.x); o[1] = (short)f2bf(v.y);
        o[2] = (short)f2bf(v.z); o[3] = (short)f2bf(v.w);
        *(bf16x4*)(wobf + e) = o;
    } else if (tid < 96) {
        int e = tid * 4;
        float4 v = *(const float4*)(bias + e);
        float s = (e < 128) ? Q_PRESCALE : 1.f;
        v.x *= s; v.y *= s; v.z *= s; v.w *= s;
        *(float4*)(biasf + e) = v;
    } else if (tid < 128) {
        int e = (tid - 96) * 4;
        *(float4*)(biasf + 384 + e) = *(const float4*)(bo + e);
    }
}

// ---------------- Kernel 1: QKV projection, bf16 MFMA ----------------
__global__ __launch_bounds__(256)
void qkv_mfma_kernel(const float* __restrict__ x,
                     const __hip_bfloat16* __restrict__ wbf,
                     const float* __restrict__ biasf,
                     __hip_bfloat16* __restrict__ qb,
                     __hip_bfloat16* __restrict__ kb,
                     __hip_bfloat16* __restrict__ vtb)
{
    __shared__ __align__(16) unsigned char smem[17408 + 32768];
    __hip_bfloat16* xs = (__hip_bfloat16*)smem;            // [64][136] padded
    __hip_bfloat16* wl = (__hip_bfloat16*)(smem + 17408);  // [128][128] XOR-swz
    const int tid   = threadIdx.x;
    const int mt    = blockIdx.x;
    const int which = blockIdx.y;        // 0=q 1=k 2=v
    const int b0 = (mt & 7) * 4;
    const int s0 = (mt >> 3) * 16;

    const __hip_bfloat16* wsec = wbf + which * (128 * 128);
    #pragma unroll
    for (int j = 0; j < 8; ++j) {
        int idx = tid + j * 256;
        int fl = idx >> 4, c = idx & 15;
        int cs = c ^ (fl & 15);
        gl_lds16(wsec + fl * 128 + cs * 8, wl + idx * 8);
    }
    #pragma unroll
    for (int j = 0; j < 8; ++j) {
        int idx = tid + j * 256;
        int lt = idx >> 5, c4 = idx & 31;
        int t = (s0 + (lt & 15)) * 32 + b0 + (lt >> 4);
        float4 v = *(const float4*)(x + (size_t)t * 128 + c4 * 4);
        bf16x4 o;
        o[0] = (short)f2bf(v.x); o[1] = (short)f2bf(v.y);
        o[2] = (short)f2bf(v.z); o[3] = (short)f2bf(v.w);
        *(bf16x4*)(xs + lt * 136 + c4 * 4) = o;
    }
    __syncthreads();

    const int wv = tid >> 6, wm = wv >> 1, wn = wv & 1;
    const int l = tid & 63, q15 = l & 15, g = l >> 4;

    bf16x8 xf[2][4];
    #pragma unroll
    for (int tt = 0; tt < 2; ++tt)
        #pragma unroll
        for (int kc = 0; kc < 4; ++kc)
            xf[tt][kc] = *(const bf16x8*)(xs + (wm * 32 + tt * 16 + q15) * 136
                                          + kc * 32 + 8 * g);

    f32x4 acc[4][2];
    #pragma unroll
    for (int nt = 0; nt < 4; ++nt)
        #pragma unroll
        for (int tt = 0; tt < 2; ++tt)
            acc[nt][tt] = (f32x4){0.f, 0.f, 0.f, 0.f};

    #pragma unroll
    for (int nt = 0; nt < 4; ++nt) {
        const int fl = wn * 64 + nt * 16 + q15;
        #pragma unroll
        for (int kc = 0; kc < 4; ++kc) {
            bf16x8 wf = *(const bf16x8*)(wl + fl * 128
                                         + (((kc * 4 + g) ^ q15) * 8));
            acc[nt][0] = __builtin_amdgcn_mfma_f32_16x16x32_bf16(wf, xf[0][kc], acc[nt][0], 0, 0, 0);
            acc[nt][1] = __builtin_amdgcn_mfma_f32_16x16x32_bf16(wf, xf[1][kc], acc[nt][1], 0, 0, 0);
        }
    }
    __syncthreads();
    __hip_bfloat16* ol = wl;

    if (which < 2) {
        #pragma unroll
        for (int nt = 0; nt < 4; ++nt) {
            float4 bv = *(const float4*)(biasf + which * 128 + wn * 64 + nt * 16 + 4 * g);
            #pragma unroll
            for (int tt = 0; tt < 2; ++tt) {
                bf16x4 pk;
                pk[0] = (short)f2bf(acc[nt][tt][0] + bv.x);
                pk[1] = (short)f2bf(acc[nt][tt][1] + bv.y);
                pk[2] = (short)f2bf(acc[nt][tt][2] + bv.z);
                pk[3] = (short)f2bf(acc[nt][tt][3] + bv.w);
                *(bf16x4*)(ol + (wm * 32 + tt * 16 + q15) * 136
                           + wn * 64 + nt * 16 + 4 * g) = pk;
            }
        }
        __syncthreads();
        const int bb = tid >> 6, rr = tid & 63, ss = rr >> 2, c4 = rr & 3;
        __hip_bfloat16* dst = (which == 0) ? qb : kb;
        #pragma unroll
        for (int i = 0; i < 4; ++i) {
            bf16x8 vv = *(const bf16x8*)(ol + (bb * 16 + ss) * 136 + i * 32 + c4 * 8);
            *(bf16x8*)(dst + ((size_t)((b0 + bb) * 4 + i)) * 32768
                       + (s0 + ss) * 32 + c4 * 8) = vv;
        }
    } else {
        #pragma unroll
        for (int nt = 0; nt < 4; ++nt) {
            float4 bv = *(const float4*)(biasf + 256 + wn * 64 + nt * 16 + 4 * g);
            const float* bvp = (const float*)&bv;
            #pragma unroll
            for (int tt = 0; tt < 2; ++tt) {
                #pragma unroll
                for (int r = 0; r < 4; ++r) {
                    int f = wn * 64 + nt * 16 + 4 * g + r;
                    ol[f * 72 + wm * 32 + tt * 16 + q15] =
                        __float2bfloat16(acc[nt][tt][r] + bvp[r]);
                }
            }
        }
        __syncthreads();
        const int bb = tid >> 6, rr = tid & 63, fln = rr >> 1, sh = rr & 1;
        #pragma unroll
        for (int i = 0; i < 4; ++i) {
            int f = i * 32 + fln;
            bf16x8 vv = *(const bf16x8*)(ol + f * 72 + bb * 16 + sh * 8);
            *(bf16x8*)(vtb + ((size_t)((b0 + bb) * 4 + i)) * 32768
                       + (size_t)fln * 1024 + s0 + sh * 8) = vv;
        }
    }
}

// ---------------- Kernel 2: flash attention, LDS-staged, register-P ---------
// grid (BH=128, 8), block 256 (4 waves x 32 queries). K/V double-buffered in
// LDS; V 16B-granule XOR-swizzled. No softmax max; P packed to bf16 in
// registers (A-operand, sigma_g key order); V/K fragments SHARED between the
// two query sub-tiles. Ones-B-operand MFMA row sums (lane-local).
__global__ __launch_bounds__(256)
void attn_kernel(const __hip_bfloat16* __restrict__ qg,
                 const __hip_bfloat16* __restrict__ kg,
                 const __hip_bfloat16* __restrict__ vtg,
                 __hip_bfloat16* __restrict__ att)
{
    __shared__ __hip_bfloat16 Kl[2][64 * 32];
    __shared__ __hip_bfloat16 Vl[2][32 * 64];

    const int tid = threadIdx.x;
    const int w   = tid >> 6;
    const int l   = tid & 63;
    const int q15 = l & 15;
    const int g   = l >> 4;
    const int bh  = blockIdx.x;
    const int qt  = blockIdx.y;          // 0..7, 128 queries per block

    const __hip_bfloat16* kp  = kg  + (size_t)bh * (S_LEN * HDIM);
    const __hip_bfloat16* vtp = vtg + (size_t)bh * (HDIM * S_LEN);

    const int qrow = qt * 128 + w * 32 + q15;
    const __hip_bfloat16* qbase = qg + (size_t)bh * (S_LEN * HDIM);
    bf16x8 qf0 = *(const bf16x8*)(qbase + (size_t)qrow * HDIM + 8 * g);
    bf16x8 qf1 = *(const bf16x8*)(qbase + (size_t)(qrow + 16) * HDIM + 8 * g);

    f32x4 acc00 = {0.f,0.f,0.f,0.f}, acc01 = {0.f,0.f,0.f,0.f}, accs0 = {0.f,0.f,0.f,0.f};
    f32x4 acc10 = {0.f,0.f,0.f,0.f}, acc11 = {0.f,0.f,0.f,0.f}, accs1 = {0.f,0.f,0.f,0.f};

    const short ONE = (short)0x3F80;
    const bf16x8 onef = {ONE, ONE, ONE, ONE, ONE, ONE, ONE, ONE};

    const int kkey = tid >> 2, kd0 = (tid & 3) * 8;
    // V staging: LDS 16B-granule c of row vd holds global granule c^(vd&7)
    const int vd = tid >> 3;
    const int vg0 = ((tid & 7) ^ (vd & 7)) * 8;

    gl_lds16(kp + (size_t)kkey * HDIM + kd0, (void*)(&Kl[0][0] + tid * 8));
    gl_lds16(vtp + (size_t)vd * S_LEN + vg0, (void*)(&Vl[0][0] + tid * 8));
    __syncthreads();

    // V read addressing (per lane): rows d0=q15, d1=16+q15 (same &7), byte
    // offset within 16B granule = (g&1)*8; global granule Ga=kc*4+(g>>1),
    // Gb=Ga+2; LDS granule = G ^ (row&7).
    const int vxor = q15 & 7;
    const int vbo  = (g & 1) * 8;
    const int gh   = g >> 1;

    int cur = 0;
    for (int kt = 0; kt < 16; ++kt) {
        if (kt + 1 < 16) {
            const int kb2 = (kt + 1) * 64;
            gl_lds16(kp + (size_t)(kb2 + kkey) * HDIM + kd0,
                     (void*)(&Kl[cur ^ 1][0] + tid * 8));
            gl_lds16(vtp + (size_t)vd * S_LEN + kb2 + vg0,
                     (void*)(&Vl[cur ^ 1][0] + tid * 8));
        }

        // ---- QK^T: 4 shared K reads, 8 MFMAs
        f32x4 sc0[4], sc1[4];
        #pragma unroll
        for (int sub = 0; sub < 4; ++sub) {
            bf16x8 kf = *(const bf16x8*)(&Kl[cur][(sub * 16 + q15) * HDIM + 8 * g]);
            f32x4 z = {0.f, 0.f, 0.f, 0.f};
            sc0[sub] = __builtin_amdgcn_mfma_f32_16x16x32_bf16(kf, qf0, z, 0, 0, 0);
            sc1[sub] = __builtin_amdgcn_mfma_f32_16x16x32_bf16(kf, qf1, z, 0, 0, 0);
        }

        // ---- V B-fragments (shared by both q sub-tiles): 8 swizzled b64
        const char* vbase = (const char*)&Vl[cur][0];
        bf16x8 vf00, vf01, vf10, vf11;
        {
            const int Ga0 = gh,     Gb0 = gh + 2;      // kc = 0
            const int Ga1 = 4 + gh, Gb1 = 6 + gh;      // kc = 1
            bf16x4 a0 = *(const bf16x4*)(vbase + q15 * 128 + ((Ga0 ^ vxor) * 16) + vbo);
            bf16x4 a1 = *(const bf16x4*)(vbase + q15 * 128 + ((Gb0 ^ vxor) * 16) + vbo);
            bf16x4 b0 = *(const bf16x4*)(vbase + (16 + q15) * 128 + ((Ga0 ^ vxor) * 16) + vbo);
            bf16x4 b1 = *(const bf16x4*)(vbase + (16 + q15) * 128 + ((Gb0 ^ vxor) * 16) + vbo);
            bf16x4 c0 = *(const bf16x4*)(vbase + q15 * 128 + ((Ga1 ^ vxor) * 16) + vbo);
            bf16x4 c1 = *(const bf16x4*)(vbase + q15 * 128 + ((Gb1 ^ vxor) * 16) + vbo);
            bf16x4 d0 = *(const bf16x4*)(vbase + (16 + q15) * 128 + ((Ga1 ^ vxor) * 16) + vbo);
            bf16x4 d1 = *(const bf16x4*)(vbase + (16 + q15) * 128 + ((Gb1 ^ vxor) * 16) + vbo);
            vf00 = __builtin_shufflevector(a0, a1, 0, 1, 2, 3, 4, 5, 6, 7);
            vf01 = __builtin_shufflevector(b0, b1, 0, 1, 2, 3, 4, 5, 6, 7);
            vf10 = __builtin_shufflevector(c0, c1, 0, 1, 2, 3, 4, 5, 6, 7);
            vf11 = __builtin_shufflevector(d0, d1, 0, 1, 2, 3, 4, 5, 6, 7);
        }

        // ---- P = exp2(sc) packed to bf16 A-fragments in registers
        bf16x8 pf00, pf01, pf10, pf11;
        {
            u32x4 t;
            float e0, e1, e2, e3, e4, e5, e6, e7;
#define PACKP(dst, SA, SB)                                                \
            e0 = __builtin_amdgcn_exp2f(SA[0]);                           \
            e1 = __builtin_amdgcn_exp2f(SA[1]);                           \
            e2 = __builtin_amdgcn_exp2f(SA[2]);                           \
            e3 = __builtin_amdgcn_exp2f(SA[3]);                           \
            e4 = __builtin_amdgcn_exp2f(SB[0]);                           \
            e5 = __builtin_amdgcn_exp2f(SB[1]);                           \
            e6 = __builtin_amdgcn_exp2f(SB[2]);                           \
            e7 = __builtin_amdgcn_exp2f(SB[3]);                           \
            t[0] = __builtin_amdgcn_perm(__float_as_uint(e1),             \
                                         __float_as_uint(e0), 0x07060302u); \
            t[1] = __builtin_amdgcn_perm(__float_as_uint(e3),             \
                                         __float_as_uint(e2), 0x07060302u); \
            t[2] = __builtin_amdgcn_perm(__float_as_uint(e5),             \
                                         __float_as_uint(e4), 0x07060302u); \
            t[3] = __builtin_amdgcn_perm(__float_as_uint(e7),             \
                                         __float_as_uint(e6), 0x07060302u); \
            __builtin_memcpy(&dst, &t, 16);

            PACKP(pf00, sc0[0], sc0[1])
            PACKP(pf01, sc0[2], sc0[3])
            PACKP(pf10, sc1[0], sc1[1])
            PACKP(pf11, sc1[2], sc1[3])
#undef PACKP
        }

        // ---- PV + ones row-sums: 12 MFMAs, shared V fragments
        acc00 = __builtin_amdgcn_mfma_f32_16x16x32_bf16(pf00, vf00, acc00, 0, 0, 0);
        acc01 = __builtin_amdgcn_mfma_f32_16x16x32_bf16(pf00, vf01, acc01, 0, 0, 0);
        accs0 = __builtin_amdgcn_mfma_f32_16x16x32_bf16(pf00, onef, accs0, 0, 0, 0);
        acc10 = __builtin_amdgcn_mfma_f32_16x16x32_bf16(pf10, vf00, acc10, 0, 0, 0);
        acc11 = __builtin_amdgcn_mfma_f32_16x16x32_bf16(pf10, vf01, acc11, 0, 0, 0);
        accs1 = __builtin_amdgcn_mfma_f32_16x16x32_bf16(pf10, onef, accs1, 0, 0, 0);
        acc00 = __builtin_amdgcn_mfma_f32_16x16x32_bf16(pf01, vf10, acc00, 0, 0, 0);
        acc01 = __builtin_amdgcn_mfma_f32_16x16x32_bf16(pf01, vf11, acc01, 0, 0, 0);
        accs0 = __builtin_amdgcn_mfma_f32_16x16x32_bf16(pf01, onef, accs0, 0, 0, 0);
        acc10 = __builtin_amdgcn_mfma_f32_16x16x32_bf16(pf11, vf10, acc10, 0, 0, 0);
        acc11 = __builtin_amdgcn_mfma_f32_16x16x32_bf16(pf11, vf11, acc11, 0, 0, 0);
        accs1 = __builtin_amdgcn_mfma_f32_16x16x32_bf16(pf11, onef, accs1, 0, 0, 0);

        __syncthreads();   // drains vmcnt: next tile staged; compute done
        cur ^= 1;
    }

    // ---- epilogue: normalize by ones row sums (lane-local), write bf16
    // acc00[r]=O[q=4g+r][d=q15], acc01[r]=O[q=4g+r][d=16+q15] (sub-tile 0);
    // acc1x likewise for queries +16.
    const int b = bh >> 2, h = bh & 3;
    #pragma unroll
    for (int r = 0; r < 4; ++r) {
        const float i0 = 1.f / accs0[r];
        const float i1 = 1.f / accs1[r];
        const int s0r = qt * 128 + w * 32 + 4 * g + r;
        __hip_bfloat16* ap0 = att + ((size_t)s0r * BATCH + b) * EMB + h * HDIM;
        __hip_bfloat16* ap1 = att + ((size_t)(s0r + 16) * BATCH + b) * EMB + h * HDIM;
        ap0[q15]      = __float2bfloat16(acc00[r] * i0);
        ap0[16 + q15] = __float2bfloat16(acc01[r] * i0);
        ap1[q15]      = __float2bfloat16(acc10[r] * i1);
        ap1[16 + q15] = __float2bfloat16(acc11[r] * i1);
    }
}

// ---------------- Kernel 3: out_proj MFMA + bias + residual + LayerNorm ----
__global__ __launch_bounds__(256)
void proj_ln_mfma(const float* __restrict__ x,
                  const __hip_bfloat16* __restrict__ att,
                  const __hip_bfloat16* __restrict__ wobf,
                  const float* __restrict__ biasf,
                  const float* __restrict__ gm, const float* __restrict__ bt,
                  float* __restrict__ out)
{
    __shared__ __align__(16) unsigned char smem[32768 + 16384 + 1024];
    __hip_bfloat16* wl = (__hip_bfloat16*)smem;              // [128][128] XOR-swz
    __hip_bfloat16* al = (__hip_bfloat16*)(smem + 32768);    // [64][128] XOR-swz
    float* red = (float*)(smem + 32768 + 16384);             // [2][128]

    const int tid = threadIdx.x;
    const int t0  = blockIdx.x * 64;

    #pragma unroll
    for (int j = 0; j < 8; ++j) {
        int idx = tid + j * 256;
        int fl = idx >> 4, c = idx & 15;
        int cs = c ^ (fl & 15);
        gl_lds16(wobf + fl * 128 + cs * 8, wl + idx * 8);
    }
    #pragma unroll
    for (int j = 0; j < 4; ++j) {
        int idx = tid + j * 256;
        int fl = idx >> 4, c = idx & 15;
        int cs = c ^ (fl & 15);
        gl_lds16(att + (size_t)(t0 + fl) * 128 + cs * 8, al + idx * 8);
    }
    __syncthreads();

    const int wv = tid >> 6, wm = wv >> 1, wn = wv & 1;
    const int l = tid & 63, q15 = l & 15, g = l >> 4;

    bf16x8 af[2][4];
    #pragma unroll
    for (int tt = 0; tt < 2; ++tt)
        #pragma unroll
        for (int kc = 0; kc < 4; ++kc)
            af[tt][kc] = *(const bf16x8*)(al + (wm * 32 + tt * 16 + q15) * 128
                                          + (((kc * 4 + g) ^ q15) * 8));

    f32x4 acc[4][2];
    #pragma unroll
    for (int nt = 0; nt < 4; ++nt)
        #pragma unroll
        for (int tt = 0; tt < 2; ++tt)
            acc[nt][tt] = (f32x4){0.f, 0.f, 0.f, 0.f};

    #pragma unroll
    for (int nt = 0; nt < 4; ++nt) {
        const int fl = wn * 64 + nt * 16 + q15;
        #pragma unroll
        for (int kc = 0; kc < 4; ++kc) {
            bf16x8 wf = *(const bf16x8*)(wl + fl * 128
                                         + (((kc * 4 + g) ^ q15) * 8));
            acc[nt][0] = __builtin_amdgcn_mfma_f32_16x16x32_bf16(wf, af[0][kc], acc[nt][0], 0, 0, 0);
            acc[nt][1] = __builtin_amdgcn_mfma_f32_16x16x32_bf16(wf, af[1][kc], acc[nt][1], 0, 0, 0);
        }
    }

    float vv[4][2][4];
    float psum[2] = {0.f, 0.f}, psq[2] = {0.f, 0.f};
    #pragma unroll
    for (int nt = 0; nt < 4; ++nt) {
        const int f0 = wn * 64 + nt * 16 + 4 * g;
        float4 bv = *(const float4*)(biasf + 384 + f0);
        const float* bvp = (const float*)&bv;
        #pragma unroll
        for (int tt = 0; tt < 2; ++tt) {
            const int t = t0 + wm * 32 + tt * 16 + q15;
            float4 xv = *(const float4*)(x + (size_t)t * 128 + f0);
            const float* xvp = (const float*)&xv;
            #pragma unroll
            for (int r = 0; r < 4; ++r) {
                float v = acc[nt][tt][r] + bvp[r] + xvp[r];
                vv[nt][tt][r] = v;
                psum[tt] += v;
                psq[tt]  = fmaf(v, v, psq[tt]);
            }
        }
    }
    #pragma unroll
    for (int tt = 0; tt < 2; ++tt) {
        psum[tt] += __shfl_xor(psum[tt], 16);
        psum[tt] += __shfl_xor(psum[tt], 32);
        psq[tt]  += __shfl_xor(psq[tt], 16);
        psq[tt]  += __shfl_xor(psq[tt], 32);
    }
    if (l < 16) {
        #pragma unroll
        for (int tt = 0; tt < 2; ++tt) {
            int idx = ((wn * 2 + wm) * 2 + tt) * 16 + q15;
            red[idx]       = psum[tt];
            red[128 + idx] = psq[tt];
        }
    }
    __syncthreads();

    float mean[2], rstd[2];
    #pragma unroll
    for (int tt = 0; tt < 2; ++tt) {
        int oidx = (((wn ^ 1) * 2 + wm) * 2 + tt) * 16 + q15;
        float s  = psum[tt] + red[oidx];
        float sq = psq[tt]  + red[128 + oidx];
        mean[tt] = s * (1.f / 128.f);
        float var = sq * (1.f / 128.f) - mean[tt] * mean[tt];
        rstd[tt] = rsqrtf(var + 1e-5f);
    }

    #pragma unroll
    for (int nt = 0; nt < 4; ++nt) {
        const int f0 = wn * 64 + nt * 16 + 4 * g;
        float4 gv  = *(const float4*)(gm + f0);
        float4 btv = *(const float4*)(bt + f0);
        const float* gvp = (const float*)&gv;
        const float* btp = (const float*)&btv;
        #pragma unroll
        for (int tt = 0; tt < 2; ++tt) {
            const int t = t0 + wm * 32 + tt * 16 + q15;
            float4 o;
            float* op = (float*)&o;
            #pragma unroll
            for (int r = 0; r < 4; ++r)
                op[r] = (vv[nt][tt][r] - mean[tt]) * rstd[tt] * gvp[r] + btp[r];
            *(float4*)(out + (size_t)t * 128 + f0) = o;
        }
    }
}

extern "C" void kernel_launch(void* const* d_in, const int* in_sizes, int n_in,
                              void* d_out, int out_size, void* d_ws, size_t ws_size,
                              hipStream_t stream) {
    const float* x     = (const float*)d_in[0];
    const float* wi    = (const float*)d_in[1];
    const float* bi    = (const float*)d_in[2];
    const float* wo    = (const float*)d_in[3];
    const float* bo    = (const float*)d_in[4];
    const float* gamma = (const float*)d_in[5];
    const float* beta  = (const float*)d_in[6];
    float* out = (float*)d_out;

    unsigned char* wsb = (unsigned char*)d_ws;
    __hip_bfloat16* wbf   = (__hip_bfloat16*)wsb;               // 98304 B
    __hip_bfloat16* wobf  = (__hip_bfloat16*)(wsb + 98304);     // 32768 B
    float*          biasf = (float*)(wsb + 131072);             // 2048 B
    __hip_bfloat16* qb    = (__hip_bfloat16*)(wsb + 133120);    // 8 MB each
    __hip_bfloat16* kb    = qb + HBUF;
    __hip_bfloat16* vtb   = kb + HBUF;
    __hip_bfloat16* att   = vtb + HBUF;                          // 8 MB

    wcvt_kernel<<<65, 256, 0, stream>>>(wi, bi, wo, bo, wbf, wobf, biasf);
    qkv_mfma_kernel<<<dim3(512, 3), 256, 0, stream>>>(x, wbf, biasf, qb, kb, vtb);
    attn_kernel<<<dim3(BHN, 8), 256, 0, stream>>>(qb, kb, vtb, att);
    proj_ln_mfma<<<512, 256, 0, stream>>>(x, att, wobf, biasf, gamma, beta, out);
}

// Round 20
// 59.273 us; speedup vs baseline: 1.1107x; 1.1075x over previous
//
#include <hip/hip_runtime.h>
#include <hip/hip_bf16.h>
#include <math.h>

#define S_LEN 1024
#define BATCH 32
#define EMB   128
#define NHEAD 4
#define HDIM  32
#define BHN   (BATCH*NHEAD)          // 128
#define HBUF  (BHN*S_LEN*HDIM)       // 4194304 elements per q/k/v (bf16)
#define NTOK  (S_LEN*BATCH)          // 32768

typedef __attribute__((ext_vector_type(4))) float f32x4;
typedef __attribute__((ext_vector_type(8))) short bf16x8;
typedef __attribute__((ext_vector_type(4))) short bf16x4;
typedef __attribute__((ext_vector_type(2))) unsigned int u32x2;
typedef __attribute__((ext_vector_type(4))) unsigned int u32x4;

// (1/sqrt(32)) * log2(e): folded into Wq/bq by wcvt_kernel
#define Q_PRESCALE 0.25503588f

__device__ __forceinline__ unsigned short f2bf(float f) {
    union { float f; unsigned u; } v; v.f = f;
    unsigned r = v.u + 0x7fff + ((v.u >> 16) & 1);   // RNE
    return (unsigned short)(r >> 16);
}

__device__ __forceinline__ void gl_lds16(const void* g, void* l) {
    __builtin_amdgcn_global_load_lds(
        (const __attribute__((address_space(1))) unsigned*)g,
        (__attribute__((address_space(3))) unsigned*)l, 16, 0, 0);
}

// ---------------- Kernel 0: weight/bias convert (fp32 -> bf16) -------------
__global__ __launch_bounds__(256)
void wcvt_kernel(const float* __restrict__ w, const float* __restrict__ bias,
                 const float* __restrict__ wo, const float* __restrict__ bo,
                 __hip_bfloat16* __restrict__ wbf,
                 __hip_bfloat16* __restrict__ wobf,
                 float* __restrict__ biasf)
{
    const int bid = blockIdx.x, tid = threadIdx.x;
    if (bid < 48) {
        int e = bid * 1024 + tid * 4;
        float4 v = *(const float4*)(w + e);
        float s = (e < 128 * 128) ? Q_PRESCALE : 1.f;
        bf16x4 o;
        o[0] = (short)f2bf(v.x * s); o[1] = (short)f2bf(v.y * s);
        o[2] = (short)f2bf(v.z * s); o[3] = (short)f2bf(v.w * s);
        *(bf16x4*)(wbf + e) = o;
    } else if (bid < 64) {
        int e = (bid - 48) * 1024 + tid * 4;
        float4 v = *(const float4*)(wo + e);
        bf16x4 o;
        o[0] = (short)f2bf(v.x); o[1] = (short)f2bf(v.y);
        o[2] = (short)f2bf(v.z); o[3] = (short)f2bf(v.w);
        *(bf16x4*)(wobf + e) = o;
    } else if (tid < 96) {
        int e = tid * 4;
        float4 v = *(const float4*)(bias + e);
        float s = (e < 128) ? Q_PRESCALE : 1.f;
        v.x *= s; v.y *= s; v.z *= s; v.w *= s;
        *(float4*)(biasf + e) = v;
    } else if (tid < 128) {
        int e = (tid - 96) * 4;
        *(float4*)(biasf + 384 + e) = *(const float4*)(bo + e);
    }
}

// ---------------- Kernel 1: QKV projection, bf16 MFMA ----------------
__global__ __launch_bounds__(256)
void qkv_mfma_kernel(const float* __restrict__ x,
                     const __hip_bfloat16* __restrict__ wbf,
                     const float* __restrict__ biasf,
                     __hip_bfloat16* __restrict__ qb,
                     __hip_bfloat16* __restrict__ kb,
                     __hip_bfloat16* __restrict__ vtb)
{
    __shared__ __align__(16) unsigned char smem[17408 + 32768];
    __hip_bfloat16* xs = (__hip_bfloat16*)smem;            // [64][136] padded
    __hip_bfloat16* wl = (__hip_bfloat16*)(smem + 17408);  // [128][128] XOR-swz
    const int tid   = threadIdx.x;
    const int mt    = blockIdx.x;
    const int which = blockIdx.y;        // 0=q 1=k 2=v
    const int b0 = (mt & 7) * 4;
    const int s0 = (mt >> 3) * 16;

    const __hip_bfloat16* wsec = wbf + which * (128 * 128);
    #pragma unroll
    for (int j = 0; j < 8; ++j) {
        int idx = tid + j * 256;
        int fl = idx >> 4, c = idx & 15;
        int cs = c ^ (fl & 15);
        gl_lds16(wsec + fl * 128 + cs * 8, wl + idx * 8);
    }
    #pragma unroll
    for (int j = 0; j < 8; ++j) {
        int idx = tid + j * 256;
        int lt = idx >> 5, c4 = idx & 31;
        int t = (s0 + (lt & 15)) * 32 + b0 + (lt >> 4);
        float4 v = *(const float4*)(x + (size_t)t * 128 + c4 * 4);
        bf16x4 o;
        o[0] = (short)f2bf(v.x); o[1] = (short)f2bf(v.y);
        o[2] = (short)f2bf(v.z); o[3] = (short)f2bf(v.w);
        *(bf16x4*)(xs + lt * 136 + c4 * 4) = o;
    }
    __syncthreads();

    const int wv = tid >> 6, wm = wv >> 1, wn = wv & 1;
    const int l = tid & 63, q15 = l & 15, g = l >> 4;

    bf16x8 xf[2][4];
    #pragma unroll
    for (int tt = 0; tt < 2; ++tt)
        #pragma unroll
        for (int kc = 0; kc < 4; ++kc)
            xf[tt][kc] = *(const bf16x8*)(xs + (wm * 32 + tt * 16 + q15) * 136
                                          + kc * 32 + 8 * g);

    f32x4 acc[4][2];
    #pragma unroll
    for (int nt = 0; nt < 4; ++nt)
        #pragma unroll
        for (int tt = 0; tt < 2; ++tt)
            acc[nt][tt] = (f32x4){0.f, 0.f, 0.f, 0.f};

    #pragma unroll
    for (int nt = 0; nt < 4; ++nt) {
        const int fl = wn * 64 + nt * 16 + q15;
        #pragma unroll
        for (int kc = 0; kc < 4; ++kc) {
            bf16x8 wf = *(const bf16x8*)(wl + fl * 128
                                         + (((kc * 4 + g) ^ q15) * 8));
            acc[nt][0] = __builtin_amdgcn_mfma_f32_16x16x32_bf16(wf, xf[0][kc], acc[nt][0], 0, 0, 0);
            acc[nt][1] = __builtin_amdgcn_mfma_f32_16x16x32_bf16(wf, xf[1][kc], acc[nt][1], 0, 0, 0);
        }
    }
    __syncthreads();
    __hip_bfloat16* ol = wl;

    if (which < 2) {
        #pragma unroll
        for (int nt = 0; nt < 4; ++nt) {
            float4 bv = *(const float4*)(biasf + which * 128 + wn * 64 + nt * 16 + 4 * g);
            #pragma unroll
            for (int tt = 0; tt < 2; ++tt) {
                bf16x4 pk;
                pk[0] = (short)f2bf(acc[nt][tt][0] + bv.x);
                pk[1] = (short)f2bf(acc[nt][tt][1] + bv.y);
                pk[2] = (short)f2bf(acc[nt][tt][2] + bv.z);
                pk[3] = (short)f2bf(acc[nt][tt][3] + bv.w);
                *(bf16x4*)(ol + (wm * 32 + tt * 16 + q15) * 136
                           + wn * 64 + nt * 16 + 4 * g) = pk;
            }
        }
        __syncthreads();
        const int bb = tid >> 6, rr = tid & 63, ss = rr >> 2, c4 = rr & 3;
        __hip_bfloat16* dst = (which == 0) ? qb : kb;
        #pragma unroll
        for (int i = 0; i < 4; ++i) {
            bf16x8 vv = *(const bf16x8*)(ol + (bb * 16 + ss) * 136 + i * 32 + c4 * 8);
            *(bf16x8*)(dst + ((size_t)((b0 + bb) * 4 + i)) * 32768
                       + (s0 + ss) * 32 + c4 * 8) = vv;
        }
    } else {
        #pragma unroll
        for (int nt = 0; nt < 4; ++nt) {
            float4 bv = *(const float4*)(biasf + 256 + wn * 64 + nt * 16 + 4 * g);
            const float* bvp = (const float*)&bv;
            #pragma unroll
            for (int tt = 0; tt < 2; ++tt) {
                #pragma unroll
                for (int r = 0; r < 4; ++r) {
                    int f = wn * 64 + nt * 16 + 4 * g + r;
                    ol[f * 72 + wm * 32 + tt * 16 + q15] =
                        __float2bfloat16(acc[nt][tt][r] + bvp[r]);
                }
            }
        }
        __syncthreads();
        const int bb = tid >> 6, rr = tid & 63, fln = rr >> 1, sh = rr & 1;
        #pragma unroll
        for (int i = 0; i < 4; ++i) {
            int f = i * 32 + fln;
            bf16x8 vv = *(const bf16x8*)(ol + f * 72 + bb * 16 + sh * 8);
            *(bf16x8*)(vtb + ((size_t)((b0 + bb) * 4 + i)) * 32768
                       + (size_t)fln * 1024 + s0 + sh * 8) = vv;
        }
    }
}

// ---------------- Kernel 2: flash attention, counted-vmcnt pipeline ---------
// grid (BH=128, 8), block 256 (4 waves x 32 queries). K/V TRIPLE-buffered in
// LDS: stage tile t+2 while computing t; raw s_barrier with counted
// s_waitcnt vmcnt(2) (t+1's loads landed, t+2's stay in flight) -- the T4
// recipe; no full vmcnt(0) drain in the steady loop. Register-P PV (sigma_g
// key order), shared K/V fragments across the 2 query sub-tiles, no softmax
// max, ones-B-operand MFMA row sums.
__global__ __launch_bounds__(256)
void attn_kernel(const __hip_bfloat16* __restrict__ qg,
                 const __hip_bfloat16* __restrict__ kg,
                 const __hip_bfloat16* __restrict__ vtg,
                 __hip_bfloat16* __restrict__ att)
{
    __shared__ __hip_bfloat16 Kl[3][64 * 32];
    __shared__ __hip_bfloat16 Vl[3][32 * 64];

    const int tid = threadIdx.x;
    const int w   = tid >> 6;
    const int l   = tid & 63;
    const int q15 = l & 15;
    const int g   = l >> 4;
    const int bh  = blockIdx.x;
    const int qt  = blockIdx.y;          // 0..7, 128 queries per block

    const __hip_bfloat16* kp  = kg  + (size_t)bh * (S_LEN * HDIM);
    const __hip_bfloat16* vtp = vtg + (size_t)bh * (HDIM * S_LEN);

    const int qrow = qt * 128 + w * 32 + q15;
    const __hip_bfloat16* qbase = qg + (size_t)bh * (S_LEN * HDIM);
    bf16x8 qf0 = *(const bf16x8*)(qbase + (size_t)qrow * HDIM + 8 * g);
    bf16x8 qf1 = *(const bf16x8*)(qbase + (size_t)(qrow + 16) * HDIM + 8 * g);

    f32x4 acc00 = {0.f,0.f,0.f,0.f}, acc01 = {0.f,0.f,0.f,0.f}, accs0 = {0.f,0.f,0.f,0.f};
    f32x4 acc10 = {0.f,0.f,0.f,0.f}, acc11 = {0.f,0.f,0.f,0.f}, accs1 = {0.f,0.f,0.f,0.f};

    const short ONE = (short)0x3F80;
    const bf16x8 onef = {ONE, ONE, ONE, ONE, ONE, ONE, ONE, ONE};

    const int kkey = tid >> 2, kd0 = (tid & 3) * 8;
    // V staging: LDS 16B-granule c of row vd holds global granule c^(vd&7)
    const int vd = tid >> 3;
    const int vg0 = ((tid & 7) ^ (vd & 7)) * 8;

    // V read addressing (per lane): rows d0=q15, d1=16+q15 (same &7), byte
    // offset within 16B granule = (g&1)*8; global granule Ga=kc*4+(g>>1),
    // Gb=Ga+2; LDS granule = G ^ (row&7).
    const int vxor = q15 & 7;
    const int vbo  = (g & 1) * 8;
    const int gh   = g >> 1;

#define STAGE(buf, kt_)                                                     \
    gl_lds16(kp + (size_t)((kt_) * 64 + kkey) * HDIM + kd0,                 \
             (void*)(&Kl[buf][0] + tid * 8));                               \
    gl_lds16(vtp + (size_t)vd * S_LEN + (kt_) * 64 + vg0,                   \
             (void*)(&Vl[buf][0] + tid * 8));

#define COMPUTE(buf)                                                        \
    {                                                                       \
        f32x4 sc0[4], sc1[4];                                               \
        _Pragma("unroll")                                                   \
        for (int sub = 0; sub < 4; ++sub) {                                 \
            bf16x8 kf = *(const bf16x8*)(&Kl[buf][(sub * 16 + q15) * HDIM + 8 * g]); \
            f32x4 z = {0.f, 0.f, 0.f, 0.f};                                 \
            sc0[sub] = __builtin_amdgcn_mfma_f32_16x16x32_bf16(kf, qf0, z, 0, 0, 0); \
            sc1[sub] = __builtin_amdgcn_mfma_f32_16x16x32_bf16(kf, qf1, z, 0, 0, 0); \
        }                                                                   \
        const char* vbase = (const char*)&Vl[buf][0];                       \
        bf16x8 vf00, vf01, vf10, vf11;                                      \
        {                                                                   \
            const int Ga0 = gh,     Gb0 = gh + 2;                           \
            const int Ga1 = 4 + gh, Gb1 = 6 + gh;                           \
            bf16x4 a0 = *(const bf16x4*)(vbase + q15 * 128 + ((Ga0 ^ vxor) * 16) + vbo); \
            bf16x4 a1 = *(const bf16x4*)(vbase + q15 * 128 + ((Gb0 ^ vxor) * 16) + vbo); \
            bf16x4 b0 = *(const bf16x4*)(vbase + (16 + q15) * 128 + ((Ga0 ^ vxor) * 16) + vbo); \
            bf16x4 b1 = *(const bf16x4*)(vbase + (16 + q15) * 128 + ((Gb0 ^ vxor) * 16) + vbo); \
            bf16x4 c0 = *(const bf16x4*)(vbase + q15 * 128 + ((Ga1 ^ vxor) * 16) + vbo); \
            bf16x4 c1 = *(const bf16x4*)(vbase + q15 * 128 + ((Gb1 ^ vxor) * 16) + vbo); \
            bf16x4 d0 = *(const bf16x4*)(vbase + (16 + q15) * 128 + ((Ga1 ^ vxor) * 16) + vbo); \
            bf16x4 d1 = *(const bf16x4*)(vbase + (16 + q15) * 128 + ((Gb1 ^ vxor) * 16) + vbo); \
            vf00 = __builtin_shufflevector(a0, a1, 0, 1, 2, 3, 4, 5, 6, 7); \
            vf01 = __builtin_shufflevector(b0, b1, 0, 1, 2, 3, 4, 5, 6, 7); \
            vf10 = __builtin_shufflevector(c0, c1, 0, 1, 2, 3, 4, 5, 6, 7); \
            vf11 = __builtin_shufflevector(d0, d1, 0, 1, 2, 3, 4, 5, 6, 7); \
        }                                                                   \
        bf16x8 pf00, pf01, pf10, pf11;                                      \
        {                                                                   \
            u32x4 t;                                                        \
            float e0, e1, e2, e3, e4, e5, e6, e7;                           \
            PACKP(pf00, sc0[0], sc0[1])                                     \
            PACKP(pf01, sc0[2], sc0[3])                                     \
            PACKP(pf10, sc1[0], sc1[1])                                     \
            PACKP(pf11, sc1[2], sc1[3])                                     \
        }                                                                   \
        acc00 = __builtin_amdgcn_mfma_f32_16x16x32_bf16(pf00, vf00, acc00, 0, 0, 0); \
        acc01 = __builtin_amdgcn_mfma_f32_16x16x32_bf16(pf00, vf01, acc01, 0, 0, 0); \
        accs0 = __builtin_amdgcn_mfma_f32_16x16x32_bf16(pf00, onef, accs0, 0, 0, 0); \
        acc10 = __builtin_amdgcn_mfma_f32_16x16x32_bf16(pf10, vf00, acc10, 0, 0, 0); \
        acc11 = __builtin_amdgcn_mfma_f32_16x16x32_bf16(pf10, vf01, acc11, 0, 0, 0); \
        accs1 = __builtin_amdgcn_mfma_f32_16x16x32_bf16(pf10, onef, accs1, 0, 0, 0); \
        acc00 = __builtin_amdgcn_mfma_f32_16x16x32_bf16(pf01, vf10, acc00, 0, 0, 0); \
        acc01 = __builtin_amdgcn_mfma_f32_16x16x32_bf16(pf01, vf11, acc01, 0, 0, 0); \
        accs0 = __builtin_amdgcn_mfma_f32_16x16x32_bf16(pf01, onef, accs0, 0, 0, 0); \
        acc10 = __builtin_amdgcn_mfma_f32_16x16x32_bf16(pf11, vf10, acc10, 0, 0, 0); \
        acc11 = __builtin_amdgcn_mfma_f32_16x16x32_bf16(pf11, vf11, acc11, 0, 0, 0); \
        accs1 = __builtin_amdgcn_mfma_f32_16x16x32_bf16(pf11, onef, accs1, 0, 0, 0); \
    }

#define PACKP(dst, SA, SB)                                                \
    e0 = __builtin_amdgcn_exp2f(SA[0]);                                   \
    e1 = __builtin_amdgcn_exp2f(SA[1]);                                   \
    e2 = __builtin_amdgcn_exp2f(SA[2]);                                   \
    e3 = __builtin_amdgcn_exp2f(SA[3]);                                   \
    e4 = __builtin_amdgcn_exp2f(SB[0]);                                   \
    e5 = __builtin_amdgcn_exp2f(SB[1]);                                   \
    e6 = __builtin_amdgcn_exp2f(SB[2]);                                   \
    e7 = __builtin_amdgcn_exp2f(SB[3]);                                   \
    t[0] = __builtin_amdgcn_perm(__float_as_uint(e1),                     \
                                 __float_as_uint(e0), 0x07060302u);       \
    t[1] = __builtin_amdgcn_perm(__float_as_uint(e3),                     \
                                 __float_as_uint(e2), 0x07060302u);       \
    t[2] = __builtin_amdgcn_perm(__float_as_uint(e5),                     \
                                 __float_as_uint(e4), 0x07060302u);       \
    t[3] = __builtin_amdgcn_perm(__float_as_uint(e7),                     \
                                 __float_as_uint(e6), 0x07060302u);       \
    __builtin_memcpy(&dst, &t, 16);

    // ---- prologue: stage tiles 0 and 1; wait only for tile 0
    STAGE(0, 0)
    STAGE(1, 1)
    asm volatile("s_waitcnt vmcnt(2)" ::: "memory");
    __builtin_amdgcn_s_barrier();
    asm volatile("" ::: "memory");

    // ---- steady state: stage t+2, compute t, counted-vmcnt barrier
    #pragma unroll
    for (int kt = 0; kt < 14; ++kt) {
        const int cb = kt % 3;
        const int sb = (kt + 2) % 3;
        STAGE(sb, kt + 2)
        COMPUTE(cb)
        asm volatile("s_waitcnt vmcnt(2)" ::: "memory");
        __builtin_amdgcn_s_barrier();
        asm volatile("" ::: "memory");
        __builtin_amdgcn_sched_barrier(0);
    }
    // ---- kt = 14: nothing left to stage; drain for tile 15
    COMPUTE(2)
    asm volatile("s_waitcnt vmcnt(0)" ::: "memory");
    __builtin_amdgcn_s_barrier();
    asm volatile("" ::: "memory");
    // ---- kt = 15
    COMPUTE(0)

#undef STAGE
#undef COMPUTE
#undef PACKP

    // ---- epilogue: normalize by ones row sums (lane-local), write bf16
    const int b = bh >> 2, h = bh & 3;
    #pragma unroll
    for (int r = 0; r < 4; ++r) {
        const float i0 = 1.f / accs0[r];
        const float i1 = 1.f / accs1[r];
        const int s0r = qt * 128 + w * 32 + 4 * g + r;
        __hip_bfloat16* ap0 = att + ((size_t)s0r * BATCH + b) * EMB + h * HDIM;
        __hip_bfloat16* ap1 = att + ((size_t)(s0r + 16) * BATCH + b) * EMB + h * HDIM;
        ap0[q15]      = __float2bfloat16(acc00[r] * i0);
        ap0[16 + q15] = __float2bfloat16(acc01[r] * i0);
        ap1[q15]      = __float2bfloat16(acc10[r] * i1);
        ap1[16 + q15] = __float2bfloat16(acc11[r] * i1);
    }
}

// ---------------- Kernel 3: out_proj MFMA + bias + residual + LayerNorm ----
__global__ __launch_bounds__(256)
void proj_ln_mfma(const float* __restrict__ x,
                  const __hip_bfloat16* __restrict__ att,
                  const __hip_bfloat16* __restrict__ wobf,
                  const float* __restrict__ biasf,
                  const float* __restrict__ gm, const float* __restrict__ bt,
                  float* __restrict__ out)
{
    __shared__ __align__(16) unsigned char smem[32768 + 16384 + 1024];
    __hip_bfloat16* wl = (__hip_bfloat16*)smem;              // [128][128] XOR-swz
    __hip_bfloat16* al = (__hip_bfloat16*)(smem + 32768);    // [64][128] XOR-swz
    float* red = (float*)(smem + 32768 + 16384);             // [2][128]

    const int tid = threadIdx.x;
    const int t0  = blockIdx.x * 64;

    #pragma unroll
    for (int j = 0; j < 8; ++j) {
        int idx = tid + j * 256;
        int fl = idx >> 4, c = idx & 15;
        int cs = c ^ (fl & 15);
        gl_lds16(wobf + fl * 128 + cs * 8, wl + idx * 8);
    }
    #pragma unroll
    for (int j = 0; j < 4; ++j) {
        int idx = tid + j * 256;
        int fl = idx >> 4, c = idx & 15;
        int cs = c ^ (fl & 15);
        gl_lds16(att + (size_t)(t0 + fl) * 128 + cs * 8, al + idx * 8);
    }
    __syncthreads();

    const int wv = tid >> 6, wm = wv >> 1, wn = wv & 1;
    const int l = tid & 63, q15 = l & 15, g = l >> 4;

    bf16x8 af[2][4];
    #pragma unroll
    for (int tt = 0; tt < 2; ++tt)
        #pragma unroll
        for (int kc = 0; kc < 4; ++kc)
            af[tt][kc] = *(const bf16x8*)(al + (wm * 32 + tt * 16 + q15) * 128
                                          + (((kc * 4 + g) ^ q15) * 8));

    f32x4 acc[4][2];
    #pragma unroll
    for (int nt = 0; nt < 4; ++nt)
        #pragma unroll
        for (int tt = 0; tt < 2; ++tt)
            acc[nt][tt] = (f32x4){0.f, 0.f, 0.f, 0.f};

    #pragma unroll
    for (int nt = 0; nt < 4; ++nt) {
        const int fl = wn * 64 + nt * 16 + q15;
        #pragma unroll
        for (int kc = 0; kc < 4; ++kc) {
            bf16x8 wf = *(const bf16x8*)(wl + fl * 128
                                         + (((kc * 4 + g) ^ q15) * 8));
            acc[nt][0] = __builtin_amdgcn_mfma_f32_16x16x32_bf16(wf, af[0][kc], acc[nt][0], 0, 0, 0);
            acc[nt][1] = __builtin_amdgcn_mfma_f32_16x16x32_bf16(wf, af[1][kc], acc[nt][1], 0, 0, 0);
        }
    }

    float vv[4][2][4];
    float psum[2] = {0.f, 0.f}, psq[2] = {0.f, 0.f};
    #pragma unroll
    for (int nt = 0; nt < 4; ++nt) {
        const int f0 = wn * 64 + nt * 16 + 4 * g;
        float4 bv = *(const float4*)(biasf + 384 + f0);
        const float* bvp = (const float*)&bv;
        #pragma unroll
        for (int tt = 0; tt < 2; ++tt) {
            const int t = t0 + wm * 32 + tt * 16 + q15;
            float4 xv = *(const float4*)(x + (size_t)t * 128 + f0);
            const float* xvp = (const float*)&xv;
            #pragma unroll
            for (int r = 0; r < 4; ++r) {
                float v = acc[nt][tt][r] + bvp[r] + xvp[r];
                vv[nt][tt][r] = v;
                psum[tt] += v;
                psq[tt]  = fmaf(v, v, psq[tt]);
            }
        }
    }
    #pragma unroll
    for (int tt = 0; tt < 2; ++tt) {
        psum[tt] += __shfl_xor(psum[tt], 16);
        psum[tt] += __shfl_xor(psum[tt], 32);
        psq[tt]  += __shfl_xor(psq[tt], 16);
        psq[tt]  += __shfl_xor(psq[tt], 32);
    }
    if (l < 16) {
        #pragma unroll
        for (int tt = 0; tt < 2; ++tt) {
            int idx = ((wn * 2 + wm) * 2 + tt) * 16 + q15;
            red[idx]       = psum[tt];
            red[128 + idx] = psq[tt];
        }
    }
    __syncthreads();

    float mean[2], rstd[2];
    #pragma unroll
    for (int tt = 0; tt < 2; ++tt) {
        int oidx = (((wn ^ 1) * 2 + wm) * 2 + tt) * 16 + q15;
        float s  = psum[tt] + red[oidx];
        float sq = psq[tt]  + red[128 + oidx];
        mean[tt] = s * (1.f / 128.f);
        float var = sq * (1.f / 128.f) - mean[tt] * mean[tt];
        rstd[tt] = rsqrtf(var + 1e-5f);
    }

    #pragma unroll
    for (int nt = 0; nt < 4; ++nt) {
        const int f0 = wn * 64 + nt * 16 + 4 * g;
        float4 gv  = *(const float4*)(gm + f0);
        float4 btv = *(const float4*)(bt + f0);
        const float* gvp = (const float*)&gv;
        const float* btp = (const float*)&btv;
        #pragma unroll
        for (int tt = 0; tt < 2; ++tt) {
            const int t = t0 + wm * 32 + tt * 16 + q15;
            float4 o;
            float* op = (float*)&o;
            #pragma unroll
            for (int r = 0; r < 4; ++r)
                op[r] = (vv[nt][tt][r] - mean[tt]) * rstd[tt] * gvp[r] + btp[r];
            *(float4*)(out + (size_t)t * 128 + f0) = o;
        }
    }
}

extern "C" void kernel_launch(void* const* d_in, const int* in_sizes, int n_in,
                              void* d_out, int out_size, void* d_ws, size_t ws_size,
                              hipStream_t stream) {
    const float* x     = (const float*)d_in[0];
    const float* wi    = (const float*)d_in[1];
    const float* bi    = (const float*)d_in[2];
    const float* wo    = (const float*)d_in[3];
    const float* bo    = (const float*)d_in[4];
    const float* gamma = (const float*)d_in[5];
    const float* beta  = (const float*)d_in[6];
    float* out = (float*)d_out;

    unsigned char* wsb = (unsigned char*)d_ws;
    __hip_bfloat16* wbf   = (__hip_bfloat16*)wsb;               // 98304 B
    __hip_bfloat16* wobf  = (__hip_bfloat16*)(wsb + 98304);     // 32768 B
    float*          biasf = (float*)(wsb + 131072);             // 2048 B
    __hip_bfloat16* qb    = (__hip_bfloat16*)(wsb + 133120);    // 8 MB each
    __hip_bfloat16* kb    = qb + HBUF;
    __hip_bfloat16* vtb   = kb + HBUF;
    __hip_bfloat16* att   = vtb + HBUF;                          // 8 MB

    wcvt_kernel<<<65, 256, 0, stream>>>(wi, bi, wo, bo, wbf, wobf, biasf);
    qkv_mfma_kernel<<<dim3(512, 3), 256, 0, stream>>>(x, wbf, biasf, qb, kb, vtb);
    attn_kernel<<<dim3(BHN, 8), 256, 0, stream>>>(qb, kb, vtb, att);
    proj_ln_mfma<<<512, 256, 0, stream>>>(x, att, wobf, biasf, gamma, beta, out);
}